// Round 13
// baseline (133.816 us; speedup 1.0000x reference)
//
#include <hip/hip_runtime.h>

#define NHEADS 8
#define NB 512
#define NN 1000
#define DD 128
#define HH 128
#define SDIM 384              // D*CAT
#define NSPLIT 5              // blocks per batch (200 rows each)
#define NSLOT (NSPLIT * 4)    // one partial slot per wave (20)
#define RPW 50                // rows per wave = 25 pairs

// DPP helper: x += lane-permuted x. Pure VALU, no DS pipe.
template <int CTRL>
__device__ __forceinline__ float dpp_add(float x) {
    int y = __builtin_amdgcn_update_dpp(0, __float_as_int(x), CTRL, 0xf, 0xf, true);
    return x + __int_as_float(y);
}
#define DPP_QUAD_XOR1 0xB1   // quad_perm(1,0,3,2)
#define DPP_QUAD_XOR2 0x4E   // quad_perm(2,3,0,1)
#define DPP_HALF_MIRR 0x141  // mirror within 8
#define DPP_ROW_MIRR  0x140  // mirror within 16

// ---------------- kernel 0: per-batch qw precompute (coalesced) -------------
__global__ __launch_bounds__(256) void qw_kernel(
    const float* __restrict__ state_t,   // [B][384]
    const float* __restrict__ Wq,        // [128][384]
    const float* __restrict__ Wk,        // [128][128]
    float* __restrict__ qw)              // [B][8][128]
{
    const int b = blockIdx.x;
    const int t = threadIdx.x;
    const int lane = t & 63;
    const int w = t >> 6;

    __shared__ float s_q[HH];

    float st[6];
    #pragma unroll
    for (int j = 0; j < 6; ++j) st[j] = state_t[(size_t)b * SDIM + j * 64 + lane];

    for (int it = 0; it < 16; ++it) {
        const int r0 = w * 32 + it * 2;
        const float* w0 = Wq + (size_t)r0 * SDIM;
        const float* w1 = w0 + SDIM;
        float p0 = 0.f, p1 = 0.f;
        #pragma unroll
        for (int j = 0; j < 6; ++j) {
            p0 = fmaf(w0[j * 64 + lane], st[j], p0);
            p1 = fmaf(w1[j * 64 + lane], st[j], p1);
        }
        #pragma unroll
        for (int off = 32; off >= 1; off >>= 1) {
            p0 += __shfl_xor(p0, off, 64);
            p1 += __shfl_xor(p1, off, 64);
        }
        if (lane == 0) { s_q[r0] = p0; s_q[r0 + 1] = p1; }
    }
    __syncthreads();

    {
        const int d  = t & 127;
        const int h0 = (t >> 7) * 4;
        const float sc = 0.0625f * 1.4426950408889634f;  // (1/hd) * log2(e)
        for (int hh = 0; hh < 4; ++hh) {
            const int h = h0 + hh;
            float a = 0.f;
            #pragma unroll
            for (int j = 0; j < 16; ++j)
                a = fmaf(s_q[h * 16 + j], Wk[(size_t)(h * 16 + j) * DD + d], a);
            qw[(size_t)b * NHEADS * DD + h * DD + d] = a * sc;
        }
    }
}

// Conditionally load pair `kidx` (two rows, one dwordx4: 64 unique lanes x 16B
// = 1KB, zero address duplication). Skip only if BOTH rows masked (~25%).
#define LOADP(P, kidx)                                                        \
    {                                                                         \
        if ((__builtin_amdgcn_readlane(mv, 2 * (kidx)) &                      \
             __builtin_amdgcn_readlane(mv, 2 * (kidx) + 1)) == 0) {           \
            P = *reinterpret_cast<const float4*>(cp2 + (size_t)(kidx) * (2 * DD)); \
        }                                                                     \
    }

// Process pair `kidx` held in P. Each lane: 8 heads x 4-elem partial dots;
// reduce = 4 DPP (within 16) + shfl_xor(32); per-row mask as multiplier.
#define BODYP(P, kidx)                                                        \
    {                                                                         \
        const int _m0 = __builtin_amdgcn_readlane(mv, 2 * (kidx));            \
        const int _m1 = __builtin_amdgcn_readlane(mv, 2 * (kidx) + 1);        \
        if ((_m0 & _m1) == 0) {                                               \
            const float4 C = P;                                               \
            const float _f0 = _m0 ? 0.f : 1.f;                                \
            const float _f1 = _m1 ? 0.f : 1.f;                                \
            const float mm = rowsel ? _f1 : _f0;                              \
            float ps[NHEADS];                                                 \
            _Pragma("unroll")                                                 \
            for (int h = 0; h < NHEADS; ++h)                                  \
                ps[h] = fmaf(C.w, qwr[h][3], fmaf(C.z, qwr[h][2],             \
                        fmaf(C.y, qwr[h][1], C.x * qwr[h][0])));              \
            _Pragma("unroll")                                                 \
            for (int h = 0; h < NHEADS; ++h) {                                \
                ps[h] = dpp_add<DPP_QUAD_XOR1>(ps[h]);                        \
                ps[h] = dpp_add<DPP_QUAD_XOR2>(ps[h]);                        \
                ps[h] = dpp_add<DPP_HALF_MIRR>(ps[h]);                        \
                ps[h] = dpp_add<DPP_ROW_MIRR>(ps[h]);                         \
                ps[h] += __shfl_xor(ps[h], 32, 64);                           \
                const float p = exp2f(ps[h]) * mm;                            \
                den[h] += p;                                                  \
                acc[h][0] = fmaf(p, C.x, acc[h][0]);                          \
                acc[h][1] = fmaf(p, C.y, acc[h][1]);                          \
                acc[h][2] = fmaf(p, C.z, acc[h][2]);                          \
                acc[h][3] = fmaf(p, C.w, acc[h][3]);                          \
            }                                                                 \
        }                                                                     \
    }

// ---------------- kernel 1: partial score+softmax-accumulate ----------------
// Block = (split s, batch b), 256 threads = 4 waves, wave = 50 rows (25 pairs).
// Lane l: row parity (l>>4)&1, pos = ((l>>5)<<4)|(l&15), owns floats
// [pos*4, pos*4+4) of its row -> one dwordx4 per pair = 1KB unique (no 4x
// address duplication -> TA-optimal). All 8 heads per lane (qw 32 regs).
// 3 rotating pair-buffers; masks via one lane-distributed vector + readlane.
// NO fence, NO atomics (R8: device fences ~0.7ms chip-wide).
__global__ __launch_bounds__(256, 4) void attn_partial_kernel(
    const float* __restrict__ context,   // [B][N][128]
    const int*   __restrict__ mask,      // [B][N]
    const float* __restrict__ qw,        // [B][8][128] (pre-scaled)
    float* __restrict__ part_acc,        // [B][NSLOT][8][128]
    float* __restrict__ part_den)        // [B][NSLOT][8]
{
    const int s = blockIdx.x;
    const int b = blockIdx.y;
    const int w = threadIdx.x >> 6;
    const int l = threadIdx.x & 63;
    const bool rowsel = ((l >> 4) & 1) != 0;          // which row of the pair
    const int pos = ((l >> 5) << 4) | (l & 15);       // float4-slot 0..31

    const int row0 = s * 200 + w * RPW;
    const float* cp2 = context + ((size_t)b * NN + row0) * DD
                     + (rowsel ? DD : 0) + pos * 4;
    const int* mp = mask + (size_t)b * NN + row0;

    // all 50 row-masks in one lane-distributed load
    const int mv = mp[l < RPW ? l : RPW - 1];

    // qw slices: all 8 heads, this lane's 4 floats (32 regs)
    float qwr[NHEADS][4];
    {
        const float* qwb = qw + (size_t)b * NHEADS * DD + pos * 4;
        #pragma unroll
        for (int h = 0; h < NHEADS; ++h) {
            const float4 q4 = *reinterpret_cast<const float4*>(qwb + h * DD);
            qwr[h][0] = q4.x; qwr[h][1] = q4.y; qwr[h][2] = q4.z; qwr[h][3] = q4.w;
        }
    }

    float acc[NHEADS][4] = {};
    float den[NHEADS] = {};

    // 3 rotating pair-buffers (one float4 each)
    float4 p0v, p1v, p2v;
    LOADP(p0v, 0)
    LOADP(p1v, 1)
    LOADP(p2v, 2)

    // pairs 0..20: 7 triple rounds, prefetch +3 (max 23)
    for (int it = 0; it < 7; ++it) {
        const int k = 3 * it;
        BODYP(p0v, k)     LOADP(p0v, k + 3)
        BODYP(p1v, k + 1) LOADP(p1v, k + 4)
        BODYP(p2v, k + 2) LOADP(p2v, k + 5)
    }
    // peeled tail: pairs 21..24
    BODYP(p0v, 21) LOADP(p0v, 24)
    BODYP(p1v, 22)
    BODYP(p2v, 23)
    BODYP(p0v, 24)

    // ---- fold the two row-parities (lane l <-> l^16), then write slot ----
    #pragma unroll
    for (int h = 0; h < NHEADS; ++h) {
        #pragma unroll
        for (int i = 0; i < 4; ++i)
            acc[h][i] += __shfl_xor(acc[h][i], 16, 64);
        den[h] += __shfl_xor(den[h], 16, 64);
    }

    const int slot = s * 4 + w;
    if (!rowsel) {   // lanes 0-15 (pos 0-15) and 32-47 (pos 16-31): unique pos
        float* pa_ = part_acc + (((size_t)b * NSLOT + slot) * NHEADS) * DD + pos * 4;
        #pragma unroll
        for (int h = 0; h < NHEADS; ++h)
            *reinterpret_cast<float4*>(pa_ + h * DD) =
                make_float4(acc[h][0], acc[h][1], acc[h][2], acc[h][3]);
    }
    if (l == 0) {
        float* pd = part_den + ((size_t)b * NSLOT + slot) * NHEADS;
        #pragma unroll
        for (int h = 0; h < NHEADS; ++h) pd[h] = den[h];
    }
}

// ---------------- kernel 2: combine slots + Wv/Wfc projections --------------
__global__ __launch_bounds__(128) void attn_combine_kernel(
    const float* __restrict__ part_acc,  // [B][NSLOT][8][128]
    const float* __restrict__ part_den,  // [B][NSLOT][8]
    const float* __restrict__ Wv,        // [128][128]
    const float* __restrict__ Wfc,       // [128][128]
    float* __restrict__ out)             // [B][128]
{
    const int b = blockIdx.x;
    const int t = threadIdx.x;   // 128 threads

    __shared__ float s_dn[NHEADS];
    __shared__ float s_ca[NHEADS][132];
    __shared__ float s_o2[HH];

    if (t < NHEADS) {
        float dn = 0.f;
        #pragma unroll
        for (int sp = 0; sp < NSLOT; ++sp)
            dn += part_den[((size_t)b * NSLOT + sp) * NHEADS + t];
        s_dn[t] = dn;
    }
    __syncthreads();

    {
        const int d = t;
        #pragma unroll
        for (int h = 0; h < NHEADS; ++h) {
            float a = 0.f;
            #pragma unroll
            for (int sp = 0; sp < NSLOT; ++sp)
                a += part_acc[(((size_t)b * NSLOT + sp) * NHEADS + h) * DD + d];
            s_ca[h][d] = a / s_dn[h];
        }
    }
    __syncthreads();

    {
        const int h = t >> 4;
        const float* wvr = Wv + (size_t)t * DD;
        float a = 0.f;
        #pragma unroll 4
        for (int d = 0; d < DD; ++d) a = fmaf(s_ca[h][d], wvr[d], a);
        s_o2[t] = a;
    }
    __syncthreads();

    {
        const float* wfc = Wfc + (size_t)t * DD;
        float a = 0.f;
        #pragma unroll 4
        for (int k = 0; k < DD; ++k) a = fmaf(s_o2[k], wfc[k], a);
        out[(size_t)b * HH + t] = a;
    }
}

extern "C" void kernel_launch(void* const* d_in, const int* in_sizes, int n_in,
                              void* d_out, int out_size, void* d_ws, size_t ws_size,
                              hipStream_t stream) {
    const float* state_t = (const float*)d_in[0];
    const float* context = (const float*)d_in[1];
    const int*   mask    = (const int*)d_in[2];
    const float* Wq      = (const float*)d_in[3];
    const float* Wk      = (const float*)d_in[4];
    const float* Wv      = (const float*)d_in[5];
    const float* Wfc     = (const float*)d_in[6];
    float* out = (float*)d_out;

    float* qw       = (float*)d_ws;                                  // 2 MB
    float* part_acc = qw + (size_t)NB * NHEADS * DD;                 // 21 MB
    float* part_den = part_acc + (size_t)NB * NSLOT * NHEADS * DD;   // 0.3 MB

    qw_kernel<<<dim3(NB), dim3(256), 0, stream>>>(state_t, Wq, Wk, qw);
    attn_partial_kernel<<<dim3(NSPLIT, NB), dim3(256), 0, stream>>>(
        context, mask, qw, part_acc, part_den);
    attn_combine_kernel<<<dim3(NB), dim3(128), 0, stream>>>(
        part_acc, part_den, Wv, Wfc, out);
}

// Round 14
// 95.687 us; speedup vs baseline: 1.3985x; 1.3985x over previous
//
#include <hip/hip_runtime.h>

#define NHEADS 8
#define NB 512
#define NN 1000
#define DD 128
#define HH 128
#define SDIM 384              // D*CAT
#define NSPLIT 4              // blocks per batch: 2048 blocks = EXACTLY 8/CU
#define NSLOT (NSPLIT * 4)    // one partial slot per wave (16)

// DPP helper: x += lane-permuted x. Pure VALU, no DS pipe.
template <int CTRL>
__device__ __forceinline__ float dpp_add(float x) {
    int y = __builtin_amdgcn_update_dpp(0, __float_as_int(x), CTRL, 0xf, 0xf, true);
    return x + __int_as_float(y);
}
#define DPP_QUAD_XOR1 0xB1   // quad_perm(1,0,3,2)
#define DPP_QUAD_XOR2 0x4E   // quad_perm(2,3,0,1)
#define DPP_HALF_MIRR 0x141  // mirror within 8
#define DPP_ROW_MIRR  0x140  // mirror within 16

// ---------------- kernel 0: per-batch qw precompute (coalesced) -------------
__global__ __launch_bounds__(256) void qw_kernel(
    const float* __restrict__ state_t,   // [B][384]
    const float* __restrict__ Wq,        // [128][384]
    const float* __restrict__ Wk,        // [128][128]
    float* __restrict__ qw)              // [B][8][128]
{
    const int b = blockIdx.x;
    const int t = threadIdx.x;
    const int lane = t & 63;
    const int w = t >> 6;

    __shared__ float s_q[HH];

    float st[6];
    #pragma unroll
    for (int j = 0; j < 6; ++j) st[j] = state_t[(size_t)b * SDIM + j * 64 + lane];

    for (int it = 0; it < 16; ++it) {
        const int r0 = w * 32 + it * 2;
        const float* w0 = Wq + (size_t)r0 * SDIM;
        const float* w1 = w0 + SDIM;
        float p0 = 0.f, p1 = 0.f;
        #pragma unroll
        for (int j = 0; j < 6; ++j) {
            p0 = fmaf(w0[j * 64 + lane], st[j], p0);
            p1 = fmaf(w1[j * 64 + lane], st[j], p1);
        }
        #pragma unroll
        for (int off = 32; off >= 1; off >>= 1) {
            p0 += __shfl_xor(p0, off, 64);
            p1 += __shfl_xor(p1, off, 64);
        }
        if (lane == 0) { s_q[r0] = p0; s_q[r0 + 1] = p1; }
    }
    __syncthreads();

    {
        const int d  = t & 127;
        const int h0 = (t >> 7) * 4;
        const float sc = 0.0625f * 1.4426950408889634f;  // (1/hd) * log2(e)
        for (int hh = 0; hh < 4; ++hh) {
            const int h = h0 + hh;
            float a = 0.f;
            #pragma unroll
            for (int j = 0; j < 16; ++j)
                a = fmaf(s_q[h * 16 + j], Wk[(size_t)(h * 16 + j) * DD + d], a);
            qw[(size_t)b * NHEADS * DD + h * DD + d] = a * sc;
        }
    }
}

// Wave-uniform mask for row k: SALU readlane from the lane-distributed mv.
#define MSK(kidx) (__builtin_amdgcn_readlane(mv, (kidx)))

// Conditionally load ctx row `idx` (clamped to cnt-1 via wave-uniform scalar
// select — rows past cnt-1 are dead prefetches; clamp keeps them in-bounds).
#define CLD(P, idx)                                                           \
    {                                                                         \
        const int _ci = (idx) < cnt ? (idx) : cnt - 1;                        \
        if (MSK(_ci) == 0) {                                                  \
            const float* _np = cp + (size_t)_ci * DD;                         \
            P##a = *reinterpret_cast<const float4*>(_np);                     \
            P##b = *reinterpret_cast<const float4*>(_np + 4);                 \
        }                                                                     \
    }

// Process row `idx` held in buffer P; whole body skipped for masked rows.
#define BODY(P, idx)                                                          \
    {                                                                         \
        if (MSK(idx) == 0) {                                                  \
            const float4 C0 = P##a, C1 = P##b;                                \
            float sa = C0.x * qa0.x, sb = C0.x * qb0.x;                       \
            sa = fmaf(C0.y, qa0.y, sa); sb = fmaf(C0.y, qb0.y, sb);           \
            sa = fmaf(C0.z, qa0.z, sa); sb = fmaf(C0.z, qb0.z, sb);           \
            sa = fmaf(C0.w, qa0.w, sa); sb = fmaf(C0.w, qb0.w, sb);           \
            sa = fmaf(C1.x, qa1.x, sa); sb = fmaf(C1.x, qb1.x, sb);           \
            sa = fmaf(C1.y, qa1.y, sa); sb = fmaf(C1.y, qb1.y, sb);           \
            sa = fmaf(C1.z, qa1.z, sa); sb = fmaf(C1.z, qb1.z, sb);           \
            sa = fmaf(C1.w, qa1.w, sa); sb = fmaf(C1.w, qb1.w, sb);           \
            sa = dpp_add<DPP_QUAD_XOR1>(sa); sb = dpp_add<DPP_QUAD_XOR1>(sb); \
            sa = dpp_add<DPP_QUAD_XOR2>(sa); sb = dpp_add<DPP_QUAD_XOR2>(sb); \
            sa = dpp_add<DPP_HALF_MIRR>(sa); sb = dpp_add<DPP_HALF_MIRR>(sb); \
            sa = dpp_add<DPP_ROW_MIRR>(sa);  sb = dpp_add<DPP_ROW_MIRR>(sb);  \
            const float pa = exp2f(sa);                                       \
            const float pb = exp2f(sb);                                       \
            den0 += pa; den1 += pb;                                           \
            A0.x = fmaf(pa, C0.x, A0.x); B0.x = fmaf(pb, C0.x, B0.x);         \
            A0.y = fmaf(pa, C0.y, A0.y); B0.y = fmaf(pb, C0.y, B0.y);         \
            A0.z = fmaf(pa, C0.z, A0.z); B0.z = fmaf(pb, C0.z, B0.z);         \
            A0.w = fmaf(pa, C0.w, A0.w); B0.w = fmaf(pb, C0.w, B0.w);         \
            A1.x = fmaf(pa, C1.x, A1.x); B1.x = fmaf(pb, C1.x, B1.x);         \
            A1.y = fmaf(pa, C1.y, A1.y); B1.y = fmaf(pb, C1.y, B1.y);         \
            A1.z = fmaf(pa, C1.z, A1.z); B1.z = fmaf(pb, C1.z, B1.z);         \
            A1.w = fmaf(pa, C1.w, A1.w); B1.w = fmaf(pb, C1.w, B1.w);         \
        }                                                                     \
    }

// ---------------- kernel 1: partial score+softmax-accumulate ----------------
// Block = (split s, batch b), 256 threads = 4 waves; block owns 250 rows,
// waves take 63/63/62/62 contiguous rows. Wave = 4 groups of 16 lanes; group
// g = head pair (2g,2g+1); lane j owns floats [j*8, j*8+8). All row-masks in
// one lane-distributed vector (readlane). Masked rows skip body AND loads.
// Grid = 2048 blocks = EXACTLY 8 blocks/CU (32 waves/CU, single round, zero
// residency tail). NO fence, NO atomics (R8: device fences ~0.7ms chip-wide).
__global__ __launch_bounds__(256, 4) void attn_partial_kernel(
    const float* __restrict__ context,   // [B][N][128]
    const int*   __restrict__ mask,      // [B][N]
    const float* __restrict__ qw,        // [B][8][128] (pre-scaled)
    float* __restrict__ part_acc,        // [B][NSLOT][8][128]
    float* __restrict__ part_den)        // [B][NSLOT][8]
{
    const int s = blockIdx.x;
    const int b = blockIdx.y;
    const int w = threadIdx.x >> 6;
    const int lane = threadIdx.x & 63;
    const int g = lane >> 4;     // head pair
    const int j = lane & 15;     // d-slice

    const int cnt  = (w < 2) ? 63 : 62;
    const int row0 = s * 250 + ((w < 2) ? w * 63 : 126 + (w - 2) * 62);
    const float* cp = context + ((size_t)b * NN + row0) * DD + j * 8;
    const int*   mp = mask + (size_t)b * NN + row0;

    // one load: lane i holds mask of row i (clamped; cnt <= 63 < 64)
    const int mv = mp[lane < cnt ? lane : cnt - 1];

    // qw slices for heads 2g, 2g+1 (16 regs)
    const float* qwb = qw + (size_t)b * NHEADS * DD + j * 8;
    const float4 qa0 = *reinterpret_cast<const float4*>(qwb + (2 * g) * DD);
    const float4 qa1 = *reinterpret_cast<const float4*>(qwb + (2 * g) * DD + 4);
    const float4 qb0 = *reinterpret_cast<const float4*>(qwb + (2 * g + 1) * DD);
    const float4 qb1 = *reinterpret_cast<const float4*>(qwb + (2 * g + 1) * DD + 4);

    float4 A0 = make_float4(0.f, 0.f, 0.f, 0.f), A1 = A0;  // acc head 2g
    float4 B0 = A0, B1 = A0;                                // acc head 2g+1
    float den0 = 0.f, den1 = 0.f;

    // 3 rotating single-row buffers (named locals)
    float4 p0a, p0b;
    float4 p1a, p1b;
    float4 p2a, p2b;
    CLD(p0, 0)
    CLD(p1, 1)
    CLD(p2, 2)

    // rows 0..59: 20 triple rounds; ctx prefetch +3 (clamped to cnt-1)
    for (int it = 0; it < 20; ++it) {
        const int k = 3 * it;
        BODY(p0, k)     CLD(p0, k + 3)
        BODY(p1, k + 1) CLD(p1, k + 4)
        BODY(p2, k + 2) CLD(p2, k + 5)
    }
    // peeled tail: rows 60, 61, and (waves 0-1 only) 62
    BODY(p0, 60)
    BODY(p1, 61)
    if (cnt > 62) BODY(p2, 62)

    // ---- write this wave's partial slot (no LDS, no barrier) ----
    const int slot = s * 4 + w;
    float* pa_ = part_acc + (((size_t)b * NSLOT + slot) * NHEADS) * DD + j * 8;
    *reinterpret_cast<float4*>(pa_ + (2 * g) * DD)         = A0;
    *reinterpret_cast<float4*>(pa_ + (2 * g) * DD + 4)     = A1;
    *reinterpret_cast<float4*>(pa_ + (2 * g + 1) * DD)     = B0;
    *reinterpret_cast<float4*>(pa_ + (2 * g + 1) * DD + 4) = B1;
    if (j == 0) {
        float* pd = part_den + ((size_t)b * NSLOT + slot) * NHEADS;
        pd[2 * g]     = den0;
        pd[2 * g + 1] = den1;
    }
}

// ---------------- kernel 2: combine slots + Wv/Wfc projections --------------
__global__ __launch_bounds__(128) void attn_combine_kernel(
    const float* __restrict__ part_acc,  // [B][NSLOT][8][128]
    const float* __restrict__ part_den,  // [B][NSLOT][8]
    const float* __restrict__ Wv,        // [128][128]
    const float* __restrict__ Wfc,       // [128][128]
    float* __restrict__ out)             // [B][128]
{
    const int b = blockIdx.x;
    const int t = threadIdx.x;   // 128 threads

    __shared__ float s_dn[NHEADS];
    __shared__ float s_ca[NHEADS][132];
    __shared__ float s_o2[HH];

    if (t < NHEADS) {
        float dn = 0.f;
        #pragma unroll
        for (int sp = 0; sp < NSLOT; ++sp)
            dn += part_den[((size_t)b * NSLOT + sp) * NHEADS + t];
        s_dn[t] = dn;
    }
    __syncthreads();

    {
        const int d = t;
        #pragma unroll
        for (int h = 0; h < NHEADS; ++h) {
            float a = 0.f;
            #pragma unroll
            for (int sp = 0; sp < NSLOT; ++sp)
                a += part_acc[(((size_t)b * NSLOT + sp) * NHEADS + h) * DD + d];
            s_ca[h][d] = a / s_dn[h];
        }
    }
    __syncthreads();

    {
        const int h = t >> 4;
        const float* wvr = Wv + (size_t)t * DD;
        float a = 0.f;
        #pragma unroll 4
        for (int d = 0; d < DD; ++d) a = fmaf(s_ca[h][d], wvr[d], a);
        s_o2[t] = a;
    }
    __syncthreads();

    {
        const float* wfc = Wfc + (size_t)t * DD;
        float a = 0.f;
        #pragma unroll 4
        for (int k = 0; k < DD; ++k) a = fmaf(s_o2[k], wfc[k], a);
        out[(size_t)b * HH + t] = a;
    }
}

extern "C" void kernel_launch(void* const* d_in, const int* in_sizes, int n_in,
                              void* d_out, int out_size, void* d_ws, size_t ws_size,
                              hipStream_t stream) {
    const float* state_t = (const float*)d_in[0];
    const float* context = (const float*)d_in[1];
    const int*   mask    = (const int*)d_in[2];
    const float* Wq      = (const float*)d_in[3];
    const float* Wk      = (const float*)d_in[4];
    const float* Wv      = (const float*)d_in[5];
    const float* Wfc     = (const float*)d_in[6];
    float* out = (float*)d_out;

    float* qw       = (float*)d_ws;                                  // 2 MB
    float* part_acc = qw + (size_t)NB * NHEADS * DD;                 // 33.5 MB
    float* part_den = part_acc + (size_t)NB * NSLOT * NHEADS * DD;   // 0.26 MB

    qw_kernel<<<dim3(NB), dim3(256), 0, stream>>>(state_t, Wq, Wk, qw);
    attn_partial_kernel<<<dim3(NSPLIT, NB), dim3(256), 0, stream>>>(
        context, mask, qw, part_acc, part_den);
    attn_combine_kernel<<<dim3(NB), dim3(128), 0, stream>>>(
        part_acc, part_den, Wv, Wfc, out);
}